// Round 1
// baseline (1263.457 us; speedup 1.0000x reference)
//
#include <hip/hip_runtime.h>
#include <stdint.h>

typedef float f32x4 __attribute__((ext_vector_type(4)));

#define AS1 __attribute__((address_space(1)))
#define AS3 __attribute__((address_space(3)))

__device__ __forceinline__ void async_copy16(const void* g, void* l) {
    __builtin_amdgcn_global_load_lds((AS1 void*)(g), (AS3 void*)(l), 16, 0, 0);
}

// ---------------------------------------------------------------- init
__global__ void init_kernel(unsigned* amaxs) {
    if (threadIdx.x < 2) amaxs[threadIdx.x] = 0u;
}

// ---------------------------------------------------------------- amax
__global__ void amax_kernel(const float4* __restrict__ x, int n4,
                            unsigned* __restrict__ out) {
    float m = 0.0f;
    int idx = blockIdx.x * blockDim.x + threadIdx.x;
    int stride = gridDim.x * blockDim.x;
    for (int i = idx; i < n4; i += stride) {
        float4 v = x[i];
        m = fmaxf(m, fmaxf(fmaxf(fabsf(v.x), fabsf(v.y)),
                           fmaxf(fabsf(v.z), fabsf(v.w))));
    }
#pragma unroll
    for (int off = 32; off > 0; off >>= 1)
        m = fmaxf(m, __shfl_down(m, off));
    if ((threadIdx.x & 63) == 0)
        atomicMax(out, __float_as_uint(m));
}

// ---------------------------------------------------------------- quantize
__global__ void quant_kernel(const float4* __restrict__ x, int n4,
                             const unsigned* __restrict__ amax_bits,
                             unsigned* __restrict__ q) {
    const float amax = fmaxf(__uint_as_float(*amax_bits), 1e-12f);
    const float s = 448.0f / amax;
    int idx = blockIdx.x * blockDim.x + threadIdx.x;
    int stride = gridDim.x * blockDim.x;
    for (int i = idx; i < n4; i += stride) {
        float4 v = x[i];
        float a = fminf(fmaxf(v.x * s, -448.0f), 448.0f);
        float b = fminf(fmaxf(v.y * s, -448.0f), 448.0f);
        float c = fminf(fmaxf(v.z * s, -448.0f), 448.0f);
        float d = fminf(fmaxf(v.w * s, -448.0f), 448.0f);
        int p = 0;
        p = __builtin_amdgcn_cvt_pk_fp8_f32(a, b, p, false);
        p = __builtin_amdgcn_cvt_pk_fp8_f32(c, d, p, true);
        q[i] = (unsigned)p;
    }
}

// ---------------------------------------------------------------- GEMM
// C[m,n] = sum_k A[m,k]*B[n,k]  (both fp8 e4m3, K-major)  * scale + bias[n]
// 128x128 tile, BK=64. 256 threads = 4 waves (2x2), each wave 64x64 via
// 4x4 grid of mfma_f32_16x16x32_fp8_fp8.
__global__ __launch_bounds__(256) void gemm_fp8(
    const uint8_t* __restrict__ qA,
    const uint8_t* __restrict__ qB,
    const float*   __restrict__ bias,
    const unsigned* __restrict__ amaxs,
    float* __restrict__ out,
    int M, int N, int K)
{
    __shared__ uint8_t lA[128 * 64];
    __shared__ uint8_t lB[128 * 64];

    const int tid  = threadIdx.x;
    const int lane = tid & 63;
    const int wave = tid >> 6;
    const int wm   = wave >> 1;   // 0..1
    const int wn   = wave & 1;    // 0..1
    const int mtile = blockIdx.y;
    const int ntile = blockIdx.x;

    // --- staging addressing: chunk q = tid (rows 0..63) and tid+256 (rows 64..127)
    const int ra0 = tid >> 2;              // 0..63
    const int ca0 = (tid & 3) << 4;        // byte col 0/16/32/48
    const uint8_t* gA0 = qA + (size_t)(mtile * 128 + ra0) * K + ca0;
    const uint8_t* gA1 = qA + (size_t)(mtile * 128 + ra0 + 64) * K + ca0;
    const uint8_t* gB0 = qB + (size_t)(ntile * 128 + ra0) * K + ca0;
    const uint8_t* gB1 = qB + (size_t)(ntile * 128 + ra0 + 64) * K + ca0;

    // wave-uniform LDS staging bases (HW writes base + lane*16)
    uint8_t* lA0 = lA + wave * 1024;
    uint8_t* lA1 = lA + 4096 + wave * 1024;
    uint8_t* lB0 = lB + wave * 1024;
    uint8_t* lB1 = lB + 4096 + wave * 1024;

    // --- fragment read addressing
    const int row_in = lane & 15;   // row (A) / col (B) within 16
    const int quad   = lane >> 4;   // k-group
    const uint8_t* lA_rd = lA + (wm * 64 + row_in) * 64 + quad * 8;
    const uint8_t* lB_rd = lB + (wn * 64 + row_in) * 64 + quad * 8;

    f32x4 acc[4][4] = {};

    for (int k0 = 0; k0 < K; k0 += 64) {
        async_copy16(gA0 + k0, lA0);
        async_copy16(gA1 + k0, lA1);
        async_copy16(gB0 + k0, lB0);
        async_copy16(gB1 + k0, lB1);
        __syncthreads();
#pragma unroll
        for (int ks = 0; ks < 2; ++ks) {
            long a[4], b[4];
#pragma unroll
            for (int i = 0; i < 4; ++i)
                a[i] = *(const long*)(lA_rd + i * (16 * 64) + ks * 32);
#pragma unroll
            for (int i = 0; i < 4; ++i)
                b[i] = *(const long*)(lB_rd + i * (16 * 64) + ks * 32);
#pragma unroll
            for (int i = 0; i < 4; ++i)
#pragma unroll
                for (int j = 0; j < 4; ++j)
                    acc[i][j] = __builtin_amdgcn_mfma_f32_16x16x32_fp8_fp8(
                        a[i], b[j], acc[i][j], 0, 0, 0);
        }
        __syncthreads();
    }

    // --- epilogue: out = acc * (amax_a/448)*(amax_w/448) + bias
    const float amax_a = fmaxf(__uint_as_float(amaxs[0]), 1e-12f);
    const float amax_w = fmaxf(__uint_as_float(amaxs[1]), 1e-12f);
    const float scale = (amax_a * amax_w) * (1.0f / (448.0f * 448.0f));

    const int crow0 = mtile * 128 + wm * 64 + quad * 4;
    const int ccol0 = ntile * 128 + wn * 64 + row_in;
#pragma unroll
    for (int j = 0; j < 4; ++j) {
        const int col = ccol0 + j * 16;
        const float bv = bias[col];
#pragma unroll
        for (int i = 0; i < 4; ++i) {
            const int row = crow0 + i * 16;
#pragma unroll
            for (int r = 0; r < 4; ++r) {
                out[(size_t)(row + r) * N + col] = acc[i][j][r] * scale + bv;
            }
        }
    }
}

// ---------------------------------------------------------------- launch
extern "C" void kernel_launch(void* const* d_in, const int* in_sizes, int n_in,
                              void* d_out, int out_size, void* d_ws, size_t ws_size,
                              hipStream_t stream) {
    const float* inp  = (const float*)d_in[0];
    const float* wgt  = (const float*)d_in[1];
    const float* bias = (const float*)d_in[2];
    float* out = (float*)d_out;

    const int N = in_sizes[2];              // 11008
    const int K = in_sizes[1] / N;          // 4096
    const int M = in_sizes[0] / K;          // 4096

    unsigned* amaxs = (unsigned*)d_ws;
    uint8_t* qin = (uint8_t*)d_ws + 256;
    uint8_t* qw  = qin + (size_t)M * K;

    init_kernel<<<1, 64, 0, stream>>>(amaxs);
    amax_kernel<<<2048, 256, 0, stream>>>((const float4*)inp, M * K / 4, amaxs + 0);
    amax_kernel<<<2048, 256, 0, stream>>>((const float4*)wgt, N * K / 4, amaxs + 1);
    quant_kernel<<<2048, 256, 0, stream>>>((const float4*)inp, M * K / 4, amaxs + 0, (unsigned*)qin);
    quant_kernel<<<2048, 256, 0, stream>>>((const float4*)wgt, N * K / 4, amaxs + 1, (unsigned*)qw);

    dim3 grid(N / 128, M / 128);
    gemm_fp8<<<grid, 256, 0, stream>>>(qin, qw, bias, amaxs, out, M, N, K);
}

// Round 2
// 801.690 us; speedup vs baseline: 1.5760x; 1.5760x over previous
//
#include <hip/hip_runtime.h>
#include <stdint.h>

typedef float f32x4 __attribute__((ext_vector_type(4)));

#define AS1 __attribute__((address_space(1)))
#define AS3 __attribute__((address_space(3)))

__device__ __forceinline__ void async_copy16(const void* g, void* l) {
    __builtin_amdgcn_global_load_lds((AS1 void*)(g), (AS3 void*)(l), 16, 0, 0);
}

// ---------------------------------------------------------------- init
__global__ void init_kernel(unsigned* amaxs) {
    if (threadIdx.x < 2) amaxs[threadIdx.x] = 0u;
}

// ---------------------------------------------------------------- amax (both tensors, 1 atomic/block)
__global__ __launch_bounds__(256) void amax2_kernel(
    const float4* __restrict__ x0, int n40,
    const float4* __restrict__ x1, int n41,
    int nb0, unsigned* __restrict__ amaxs)
{
    __shared__ float red[4];
    const float4* x; int n4; unsigned* dst; int bid, nb;
    if ((int)blockIdx.x < nb0) {
        x = x0; n4 = n40; dst = amaxs + 0; bid = blockIdx.x; nb = nb0;
    } else {
        x = x1; n4 = n41; dst = amaxs + 1; bid = blockIdx.x - nb0; nb = gridDim.x - nb0;
    }
    float m = 0.0f;
    int idx = bid * 256 + threadIdx.x;
    int stride = nb * 256;
    for (int i = idx; i < n4; i += stride) {
        float4 v = x[i];
        m = fmaxf(fmaxf(m, fmaxf(fabsf(v.x), fabsf(v.y))),
                  fmaxf(fabsf(v.z), fabsf(v.w)));
    }
#pragma unroll
    for (int off = 32; off > 0; off >>= 1)
        m = fmaxf(m, __shfl_down(m, off));
    if ((threadIdx.x & 63) == 0) red[threadIdx.x >> 6] = m;
    __syncthreads();
    if (threadIdx.x == 0) {
        m = fmaxf(fmaxf(red[0], red[1]), fmaxf(red[2], red[3]));
        atomicMax(dst, __float_as_uint(m));
    }
}

// ---------------------------------------------------------------- quantize (both tensors)
__global__ __launch_bounds__(256) void quant2_kernel(
    const float4* __restrict__ x0, int n40,
    const float4* __restrict__ x1, int n41,
    int nb0, const unsigned* __restrict__ amaxs,
    unsigned* __restrict__ q0, unsigned* __restrict__ q1)
{
    const float4* x; int n4; unsigned* q; int bid, nb; float amax;
    if ((int)blockIdx.x < nb0) {
        x = x0; n4 = n40; q = q0; bid = blockIdx.x; nb = nb0;
        amax = __uint_as_float(amaxs[0]);
    } else {
        x = x1; n4 = n41; q = q1; bid = blockIdx.x - nb0; nb = gridDim.x - nb0;
        amax = __uint_as_float(amaxs[1]);
    }
    const float s = 448.0f / fmaxf(amax, 1e-12f);
    int idx = bid * 256 + threadIdx.x;
    int stride = nb * 256;
    for (int i = idx; i < n4; i += stride) {
        float4 v = x[i];
        float a = fminf(fmaxf(v.x * s, -448.0f), 448.0f);
        float b = fminf(fmaxf(v.y * s, -448.0f), 448.0f);
        float c = fminf(fmaxf(v.z * s, -448.0f), 448.0f);
        float d = fminf(fmaxf(v.w * s, -448.0f), 448.0f);
        int p = 0;
        p = __builtin_amdgcn_cvt_pk_fp8_f32(a, b, p, false);
        p = __builtin_amdgcn_cvt_pk_fp8_f32(c, d, p, true);
        q[i] = (unsigned)p;
    }
}

// ---------------------------------------------------------------- GEMM
// C[m,n] = sum_k A[m,k]*B[n,k]  (fp8 e4m3, K-major)  * scale + bias[n]
// 128x128 tile, BK=64, 4 waves (2x2), 4x4 mfma_f32_16x16x32_fp8_fp8 per wave.
// LDS XOR swizzle: LDS[row][chunk c] holds global chunk c ^ f(row),
// f(r) = (r>>1)&3  -> ds_read_b64 fragment reads hit the 4-phase wave64 floor.
__global__ __launch_bounds__(256) void gemm_fp8(
    const uint8_t* __restrict__ qA,
    const uint8_t* __restrict__ qB,
    const float*   __restrict__ bias,
    const unsigned* __restrict__ amaxs,
    float* __restrict__ out,
    int M, int N, int K)
{
    __shared__ uint8_t lA[128 * 64];
    __shared__ uint8_t lB[128 * 64];

    const int tid  = threadIdx.x;
    const int lane = tid & 63;
    const int wave = tid >> 6;
    const int wm   = wave >> 1;
    const int wn   = wave & 1;
    const int mtile = blockIdx.y;
    const int ntile = blockIdx.x;

    // --- staging: thread covers LDS row ra0 (and ra0+64), 16-byte chunk slot c.
    // It loads the XOR-swizzled global chunk so reads can be conflict-free.
    const int ra0 = tid >> 2;                       // 0..63
    const int c   = tid & 3;
    const int cg0 = (c ^ ((ra0 >> 1) & 3)) << 4;    // swizzled global byte col
    // note f(ra0+64) == f(ra0)  (64>>1 = 32 ≡ 0 mod 4)
    const uint8_t* gA0 = qA + (size_t)(mtile * 128 + ra0) * K + cg0;
    const uint8_t* gA1 = qA + (size_t)(mtile * 128 + ra0 + 64) * K + cg0;
    const uint8_t* gB0 = qB + (size_t)(ntile * 128 + ra0) * K + cg0;
    const uint8_t* gB1 = qB + (size_t)(ntile * 128 + ra0 + 64) * K + cg0;

    uint8_t* lA0 = lA + wave * 1024;
    uint8_t* lA1 = lA + 4096 + wave * 1024;
    uint8_t* lB0 = lB + wave * 1024;
    uint8_t* lB1 = lB + 4096 + wave * 1024;

    // --- fragment read addressing (de-swizzled)
    const int row_in = lane & 15;
    const int quad   = lane >> 4;
    const int fr     = (row_in >> 1) & 3;
    // global kseg s = quad + 4*ks; chunk cw = (quad>>1) + 2*ks; LDS chunk = cw ^ fr
    const int aoff0 = ((((quad >> 1) + 0) ^ fr) << 4) + (quad & 1) * 8;
    const int aoff1 = ((((quad >> 1) + 2) ^ fr) << 4) + (quad & 1) * 8;
    const uint8_t* lA_rd = lA + (wm * 64 + row_in) * 64;
    const uint8_t* lB_rd = lB + (wn * 64 + row_in) * 64;

    f32x4 acc[4][4] = {};

    for (int k0 = 0; k0 < K; k0 += 64) {
        async_copy16(gA0 + k0, lA0);
        async_copy16(gA1 + k0, lA1);
        async_copy16(gB0 + k0, lB0);
        async_copy16(gB1 + k0, lB1);
        __syncthreads();
#pragma unroll
        for (int ks = 0; ks < 2; ++ks) {
            const int off = ks ? aoff1 : aoff0;
            long a[4], b[4];
#pragma unroll
            for (int i = 0; i < 4; ++i)
                a[i] = *(const long*)(lA_rd + i * 1024 + off);
#pragma unroll
            for (int i = 0; i < 4; ++i)
                b[i] = *(const long*)(lB_rd + i * 1024 + off);
#pragma unroll
            for (int i = 0; i < 4; ++i)
#pragma unroll
                for (int j = 0; j < 4; ++j)
                    acc[i][j] = __builtin_amdgcn_mfma_f32_16x16x32_fp8_fp8(
                        a[i], b[j], acc[i][j], 0, 0, 0);
        }
        __syncthreads();
    }

    // --- epilogue
    const float amax_a = fmaxf(__uint_as_float(amaxs[0]), 1e-12f);
    const float amax_w = fmaxf(__uint_as_float(amaxs[1]), 1e-12f);
    const float scale = (amax_a * amax_w) * (1.0f / (448.0f * 448.0f));

    const int crow0 = mtile * 128 + wm * 64 + quad * 4;
    const int ccol0 = ntile * 128 + wn * 64 + row_in;
#pragma unroll
    for (int j = 0; j < 4; ++j) {
        const int col = ccol0 + j * 16;
        const float bv = bias[col];
#pragma unroll
        for (int i = 0; i < 4; ++i) {
            const int row = crow0 + i * 16;
#pragma unroll
            for (int r = 0; r < 4; ++r) {
                out[(size_t)(row + r) * N + col] = acc[i][j][r] * scale + bv;
            }
        }
    }
}

// ---------------------------------------------------------------- launch
extern "C" void kernel_launch(void* const* d_in, const int* in_sizes, int n_in,
                              void* d_out, int out_size, void* d_ws, size_t ws_size,
                              hipStream_t stream) {
    const float* inp  = (const float*)d_in[0];
    const float* wgt  = (const float*)d_in[1];
    const float* bias = (const float*)d_in[2];
    float* out = (float*)d_out;

    const int N = in_sizes[2];              // 11008
    const int K = in_sizes[1] / N;          // 4096
    const int M = in_sizes[0] / K;          // 4096

    unsigned* amaxs = (unsigned*)d_ws;
    uint8_t* qin = (uint8_t*)d_ws + 256;
    uint8_t* qw  = qin + (size_t)M * K;

    const int n4i = M * K / 4;
    const int n4w = N * K / 4;
    const int nb_i = 768, nb_w = 2048;

    init_kernel<<<1, 64, 0, stream>>>(amaxs);
    amax2_kernel<<<nb_i + nb_w, 256, 0, stream>>>(
        (const float4*)inp, n4i, (const float4*)wgt, n4w, nb_i, amaxs);
    quant2_kernel<<<nb_i + nb_w, 256, 0, stream>>>(
        (const float4*)inp, n4i, (const float4*)wgt, n4w, nb_i, amaxs,
        (unsigned*)qin, (unsigned*)qw);

    dim3 grid(N / 128, M / 128);
    gemm_fp8<<<grid, 256, 0, stream>>>(qin, qw, bias, amaxs, out, M, N, K);
}